// Round 2
// baseline (6055.268 us; speedup 1.0000x reference)
//
#include <hip/hip_runtime.h>

// PillarFeatureNet scatter-sum:
//   out[c, p] = sum_{i : indices[i]==p} x[i, c]
// x: (2,000,000, 64) fp32, indices: (2,000,000) int32 in [0, 262144)
// out: (64, 262144) fp32
//
// Strategy (round 1 baseline): direct fp32 atomics into the final (C,P)
// layout. 16 lanes per point, float4 loads (wave reads 1 KB contiguous).

#define N_POINTS   2000000
#define N_FEAT     64
#define N_PILLARS  (512 * 512)

__global__ __launch_bounds__(256) void pillar_scatter_kernel(
    const float* __restrict__ x,
    const int*   __restrict__ idx,
    float*       __restrict__ out)
{
    const int lane   = threadIdx.x & 15;                       // channel quad id
    const int group  = (blockIdx.x * blockDim.x + threadIdx.x) >> 4;  // point id (initial)
    const int stride = (gridDim.x * blockDim.x) >> 4;          // point groups in grid

    const float4* __restrict__ x4 = reinterpret_cast<const float4*>(x);

    for (int i = group; i < N_POINTS; i += stride) {
        const int p = idx[i];                 // broadcast within 16-lane group
        const float4 v = x4[i * 16 + lane];   // 16 lanes x 16B = whole point row
        const int c = lane * 4;
        atomicAdd(&out[(c + 0) * N_PILLARS + p], v.x);
        atomicAdd(&out[(c + 1) * N_PILLARS + p], v.y);
        atomicAdd(&out[(c + 2) * N_PILLARS + p], v.z);
        atomicAdd(&out[(c + 3) * N_PILLARS + p], v.w);
    }
}

extern "C" void kernel_launch(void* const* d_in, const int* in_sizes, int n_in,
                              void* d_out, int out_size, void* d_ws, size_t ws_size,
                              hipStream_t stream)
{
    const float* x   = reinterpret_cast<const float*>(d_in[0]);
    const int*   idx = reinterpret_cast<const int*>(d_in[1]);
    float*       out = reinterpret_cast<float*>(d_out);

    // d_out is poisoned (0xAA) before timing and not re-poisoned between
    // replays -> must zero every call before accumulating.
    hipMemsetAsync(out, 0, (size_t)out_size * sizeof(float), stream);

    const int block = 256;
    const int grid  = 2048;   // 8 blocks/CU * 256 CU, grid-stride over points
    pillar_scatter_kernel<<<grid, block, 0, stream>>>(x, idx, out);
}

// Round 3
// 407.331 us; speedup vs baseline: 14.8657x; 14.8657x over previous
//
#include <hip/hip_runtime.h>

// PillarFeatureNet scatter-sum:
//   out[c, p] = sum_{i : indices[i]==p} x[i, c]
// x: (2,000,000, 64) fp32, indices: (2,000,000) int32 in [0, 262144)
// out: (64, 262144) fp32
//
// Round 3: counting-sort -> CSR -> gather-sum. Eliminates the 128M fp32
// atomics (R2: 21 G atomics/s, 4.36 GB beyond-L2 write traffic, 6 ms).
// Only 4M int atomics remain (L3-resident 1MB counter array).
//
// ws layout: [counts: 262144 i32][gtotal+pad: 64 i32][cursors: 262144 i32]
//            [sorted: 2,000,000 i32]   total ~10.1 MB

#define NP        2000000
#define NB        262144      // 512*512 pillars
#define SCAN_BLK  256         // threads per scan block; each thread scans 4 bins

__global__ __launch_bounds__(256) void hist_kernel(
    const int4* __restrict__ idx4, int* __restrict__ counts)
{
    const int n4 = NP / 4;
    const int stride = gridDim.x * blockDim.x;
    for (int i = blockIdx.x * blockDim.x + threadIdx.x; i < n4; i += stride) {
        const int4 v = idx4[i];
        atomicAdd(&counts[v.x], 1);
        atomicAdd(&counts[v.y], 1);
        atomicAdd(&counts[v.z], 1);
        atomicAdd(&counts[v.w], 1);
    }
}

// Each block scans 1024 bins (256 threads x 4). Block base comes from one
// atomicAdd on a global running total -> bins get a valid disjoint partition
// of [0, NP) (order across blocks is irrelevant for the final sum).
__global__ __launch_bounds__(SCAN_BLK) void scan_kernel(
    const int4* __restrict__ counts4, int* __restrict__ gtotal,
    int4* __restrict__ cursors4)
{
    __shared__ int lsum[SCAN_BLK];
    __shared__ int blockBase;
    const int tid = threadIdx.x;
    const int g = blockIdx.x * SCAN_BLK + tid;

    const int4 c = counts4[g];
    const int s = c.x + c.y + c.z + c.w;
    lsum[tid] = s;
    __syncthreads();
    #pragma unroll
    for (int off = 1; off < SCAN_BLK; off <<= 1) {
        const int v = (tid >= off) ? lsum[tid - off] : 0;
        __syncthreads();
        lsum[tid] += v;
        __syncthreads();
    }
    const int incl = lsum[tid];
    if (tid == SCAN_BLK - 1) blockBase = atomicAdd(gtotal, incl);
    __syncthreads();

    const int e = blockBase + (incl - s);      // exclusive offset of bin 4*g
    cursors4[g] = make_int4(e,
                            e + c.x,
                            e + c.x + c.y,
                            e + c.x + c.y + c.z);
}

__global__ __launch_bounds__(256) void scatter_kernel(
    const int4* __restrict__ idx4, int* __restrict__ cursors,
    int* __restrict__ sorted)
{
    const int n4 = NP / 4;
    const int stride = gridDim.x * blockDim.x;
    for (int i = blockIdx.x * blockDim.x + threadIdx.x; i < n4; i += stride) {
        const int4 v = idx4[i];
        const int base = 4 * i;
        int pos;
        pos = atomicAdd(&cursors[v.x], 1); sorted[pos] = base + 0;
        pos = atomicAdd(&cursors[v.y], 1); sorted[pos] = base + 1;
        pos = atomicAdd(&cursors[v.z], 1); sorted[pos] = base + 2;
        pos = atomicAdd(&cursors[v.w], 1); sorted[pos] = base + 3;
    }
}

// One block per 64 consecutive pillars. 16 lanes cooperate per pillar
// (lane j owns channels 4j..4j+3, float4 row gathers = 256B bursts).
// Transpose through padded LDS tile, then fully-coalesced output stores.
__global__ __launch_bounds__(256) void gather_kernel(
    const float4* __restrict__ x4,
    const int*    __restrict__ counts,
    const int*    __restrict__ ends,     // cursors after scatter = end offsets
    const int*    __restrict__ sorted,
    float*        __restrict__ out)
{
    __shared__ float tile[64][65];       // +1 pad: write conflicts 16-way -> 2-way
    const int p0 = blockIdx.x * 64;
    const int j  = threadIdx.x & 15;     // channel quad
    const int g  = threadIdx.x >> 4;     // group id (16 groups)

    #pragma unroll
    for (int k = 0; k < 4; ++k) {
        const int pl  = g + 16 * k;      // local pillar
        const int p   = p0 + pl;
        const int end = ends[p];
        const int cnt = counts[p];
        float4 acc = make_float4(0.f, 0.f, 0.f, 0.f);
        for (int t = end - cnt; t < end; ++t) {
            const int i = sorted[t];
            const float4 v = x4[(size_t)i * 16 + j];
            acc.x += v.x; acc.y += v.y; acc.z += v.z; acc.w += v.w;
        }
        tile[4 * j + 0][pl] = acc.x;
        tile[4 * j + 1][pl] = acc.y;
        tile[4 * j + 2][pl] = acc.z;
        tile[4 * j + 3][pl] = acc.w;
    }
    __syncthreads();

    const int pl    = threadIdx.x & 63;
    const int cbase = threadIdx.x >> 6;  // 0..3
    #pragma unroll
    for (int c4 = 0; c4 < 64; c4 += 4) {
        const int c = c4 + cbase;
        out[(size_t)c * NB + p0 + pl] = tile[c][pl];
    }
}

// ---- Fallback (R2 path) if workspace is too small ----
__global__ __launch_bounds__(256) void pillar_scatter_fallback(
    const float* __restrict__ x, const int* __restrict__ idx,
    float* __restrict__ out)
{
    const int lane   = threadIdx.x & 15;
    const int group  = (blockIdx.x * blockDim.x + threadIdx.x) >> 4;
    const int stride = (gridDim.x * blockDim.x) >> 4;
    const float4* __restrict__ x4 = reinterpret_cast<const float4*>(x);
    for (int i = group; i < NP; i += stride) {
        const int p = idx[i];
        const float4 v = x4[i * 16 + lane];
        const int c = lane * 4;
        atomicAdd(&out[(size_t)(c + 0) * NB + p], v.x);
        atomicAdd(&out[(size_t)(c + 1) * NB + p], v.y);
        atomicAdd(&out[(size_t)(c + 2) * NB + p], v.z);
        atomicAdd(&out[(size_t)(c + 3) * NB + p], v.w);
    }
}

extern "C" void kernel_launch(void* const* d_in, const int* in_sizes, int n_in,
                              void* d_out, int out_size, void* d_ws, size_t ws_size,
                              hipStream_t stream)
{
    const float* x   = reinterpret_cast<const float*>(d_in[0]);
    const int*   idx = reinterpret_cast<const int*>(d_in[1]);
    float*       out = reinterpret_cast<float*>(d_out);

    const size_t needed = ((size_t)2 * NB + 64 + NP) * sizeof(int);
    if (ws_size < needed) {
        // Not enough scratch: correct-but-slow atomic path.
        hipMemsetAsync(out, 0, (size_t)out_size * sizeof(float), stream);
        pillar_scatter_fallback<<<2048, 256, 0, stream>>>(x, idx, out);
        return;
    }

    int* counts  = reinterpret_cast<int*>(d_ws);
    int* gtotal  = counts + NB;
    int* cursors = counts + NB + 64;
    int* sorted  = cursors + NB;

    // Zero counts + gtotal (ws is poisoned 0xAA and never re-poisoned).
    hipMemsetAsync(counts, 0, (size_t)(NB + 64) * sizeof(int), stream);

    const int4* idx4 = reinterpret_cast<const int4*>(idx);
    hist_kernel<<<2048, 256, 0, stream>>>(idx4, counts);
    scan_kernel<<<NB / (SCAN_BLK * 4), SCAN_BLK, 0, stream>>>(
        reinterpret_cast<const int4*>(counts), gtotal,
        reinterpret_cast<int4*>(cursors));
    scatter_kernel<<<2048, 256, 0, stream>>>(idx4, cursors, sorted);
    gather_kernel<<<NB / 64, 256, 0, stream>>>(
        reinterpret_cast<const float4*>(x), counts, cursors, sorted, out);
}

// Round 4
// 406.992 us; speedup vs baseline: 14.8781x; 1.0008x over previous
//
#include <hip/hip_runtime.h>

// PillarFeatureNet scatter-sum:
//   out[c, p] = sum_{i : indices[i]==p} x[i, c]
// x: (2,000,000, 64) fp32, indices: (2,000,000) int32 in [0, 262144)
// out: (64, 262144) fp32
//
// Round 4: same CSR gather pipeline as R3, but replace hipMemsetAsync(1MB)
// with a custom zero kernel. R3 rocprof: the runtime's fillBufferAligned ran
// at 3.7 GB/s / 11% occupancy and cost 294 of 407 us.
//
// ws layout: [counts: 262144 i32][gtotal+pad: 64 i32][cursors: 262144 i32]
//            [sorted: 2,000,000 i32]   total ~10.1 MB

#define NP        2000000
#define NB        262144      // 512*512 pillars
#define SCAN_BLK  256         // threads per scan block; each thread scans 4 bins

__global__ __launch_bounds__(256) void zero_kernel(int4* __restrict__ p, int n4)
{
    const int stride = gridDim.x * blockDim.x;
    for (int i = blockIdx.x * blockDim.x + threadIdx.x; i < n4; i += stride)
        p[i] = make_int4(0, 0, 0, 0);
}

__global__ __launch_bounds__(256) void hist_kernel(
    const int4* __restrict__ idx4, int* __restrict__ counts)
{
    const int n4 = NP / 4;
    const int stride = gridDim.x * blockDim.x;
    for (int i = blockIdx.x * blockDim.x + threadIdx.x; i < n4; i += stride) {
        const int4 v = idx4[i];
        atomicAdd(&counts[v.x], 1);
        atomicAdd(&counts[v.y], 1);
        atomicAdd(&counts[v.z], 1);
        atomicAdd(&counts[v.w], 1);
    }
}

// Each block scans 1024 bins (256 threads x 4). Block base comes from one
// atomicAdd on a global running total -> bins get a valid disjoint partition
// of [0, NP) (order across blocks is irrelevant for the final sum).
__global__ __launch_bounds__(SCAN_BLK) void scan_kernel(
    const int4* __restrict__ counts4, int* __restrict__ gtotal,
    int4* __restrict__ cursors4)
{
    __shared__ int lsum[SCAN_BLK];
    __shared__ int blockBase;
    const int tid = threadIdx.x;
    const int g = blockIdx.x * SCAN_BLK + tid;

    const int4 c = counts4[g];
    const int s = c.x + c.y + c.z + c.w;
    lsum[tid] = s;
    __syncthreads();
    #pragma unroll
    for (int off = 1; off < SCAN_BLK; off <<= 1) {
        const int v = (tid >= off) ? lsum[tid - off] : 0;
        __syncthreads();
        lsum[tid] += v;
        __syncthreads();
    }
    const int incl = lsum[tid];
    if (tid == SCAN_BLK - 1) blockBase = atomicAdd(gtotal, incl);
    __syncthreads();

    const int e = blockBase + (incl - s);      // exclusive offset of bin 4*g
    cursors4[g] = make_int4(e,
                            e + c.x,
                            e + c.x + c.y,
                            e + c.x + c.y + c.z);
}

__global__ __launch_bounds__(256) void scatter_kernel(
    const int4* __restrict__ idx4, int* __restrict__ cursors,
    int* __restrict__ sorted)
{
    const int n4 = NP / 4;
    const int stride = gridDim.x * blockDim.x;
    for (int i = blockIdx.x * blockDim.x + threadIdx.x; i < n4; i += stride) {
        const int4 v = idx4[i];
        const int base = 4 * i;
        int pos;
        pos = atomicAdd(&cursors[v.x], 1); sorted[pos] = base + 0;
        pos = atomicAdd(&cursors[v.y], 1); sorted[pos] = base + 1;
        pos = atomicAdd(&cursors[v.z], 1); sorted[pos] = base + 2;
        pos = atomicAdd(&cursors[v.w], 1); sorted[pos] = base + 3;
    }
}

// One block per 64 consecutive pillars. 16 lanes cooperate per pillar
// (lane j owns channels 4j..4j+3, float4 row gathers = 256B bursts).
// Transpose through padded LDS tile, then fully-coalesced output stores.
__global__ __launch_bounds__(256) void gather_kernel(
    const float4* __restrict__ x4,
    const int*    __restrict__ counts,
    const int*    __restrict__ ends,     // cursors after scatter = end offsets
    const int*    __restrict__ sorted,
    float*        __restrict__ out)
{
    __shared__ float tile[64][65];       // +1 pad: write conflicts 16-way -> 2-way
    const int p0 = blockIdx.x * 64;
    const int j  = threadIdx.x & 15;     // channel quad
    const int g  = threadIdx.x >> 4;     // group id (16 groups)

    #pragma unroll
    for (int k = 0; k < 4; ++k) {
        const int pl  = g + 16 * k;      // local pillar
        const int p   = p0 + pl;
        const int end = ends[p];
        const int cnt = counts[p];
        float4 acc = make_float4(0.f, 0.f, 0.f, 0.f);
        for (int t = end - cnt; t < end; ++t) {
            const int i = sorted[t];
            const float4 v = x4[(size_t)i * 16 + j];
            acc.x += v.x; acc.y += v.y; acc.z += v.z; acc.w += v.w;
        }
        tile[4 * j + 0][pl] = acc.x;
        tile[4 * j + 1][pl] = acc.y;
        tile[4 * j + 2][pl] = acc.z;
        tile[4 * j + 3][pl] = acc.w;
    }
    __syncthreads();

    const int pl    = threadIdx.x & 63;
    const int cbase = threadIdx.x >> 6;  // 0..3
    #pragma unroll
    for (int c4 = 0; c4 < 64; c4 += 4) {
        const int c = c4 + cbase;
        out[(size_t)c * NB + p0 + pl] = tile[c][pl];
    }
}

// ---- Fallback (R2 path) if workspace is too small ----
__global__ __launch_bounds__(256) void pillar_scatter_fallback(
    const float* __restrict__ x, const int* __restrict__ idx,
    float* __restrict__ out)
{
    const int lane   = threadIdx.x & 15;
    const int group  = (blockIdx.x * blockDim.x + threadIdx.x) >> 4;
    const int stride = (gridDim.x * blockDim.x) >> 4;
    const float4* __restrict__ x4 = reinterpret_cast<const float4*>(x);
    for (int i = group; i < NP; i += stride) {
        const int p = idx[i];
        const float4 v = x4[i * 16 + lane];
        const int c = lane * 4;
        atomicAdd(&out[(size_t)(c + 0) * NB + p], v.x);
        atomicAdd(&out[(size_t)(c + 1) * NB + p], v.y);
        atomicAdd(&out[(size_t)(c + 2) * NB + p], v.z);
        atomicAdd(&out[(size_t)(c + 3) * NB + p], v.w);
    }
}

__global__ __launch_bounds__(256) void zero_out_kernel(float4* __restrict__ p, int n4)
{
    const int stride = gridDim.x * blockDim.x;
    for (int i = blockIdx.x * blockDim.x + threadIdx.x; i < n4; i += stride)
        p[i] = make_float4(0.f, 0.f, 0.f, 0.f);
}

extern "C" void kernel_launch(void* const* d_in, const int* in_sizes, int n_in,
                              void* d_out, int out_size, void* d_ws, size_t ws_size,
                              hipStream_t stream)
{
    const float* x   = reinterpret_cast<const float*>(d_in[0]);
    const int*   idx = reinterpret_cast<const int*>(d_in[1]);
    float*       out = reinterpret_cast<float*>(d_out);

    const size_t needed = ((size_t)2 * NB + 64 + NP) * sizeof(int);
    if (ws_size < needed) {
        // Not enough scratch: correct-but-slow atomic path.
        zero_out_kernel<<<2048, 256, 0, stream>>>(
            reinterpret_cast<float4*>(out), out_size / 4);
        pillar_scatter_fallback<<<2048, 256, 0, stream>>>(x, idx, out);
        return;
    }

    int* counts  = reinterpret_cast<int*>(d_ws);
    int* gtotal  = counts + NB;
    int* cursors = counts + NB + 64;
    int* sorted  = cursors + NB;

    // Zero counts + gtotal with our own kernel (runtime fillBufferAligned
    // ran at 3.7 GB/s and cost 294 us in R3).
    zero_kernel<<<256, 256, 0, stream>>>(
        reinterpret_cast<int4*>(counts), (NB + 64) / 4);

    const int4* idx4 = reinterpret_cast<const int4*>(idx);
    hist_kernel<<<2048, 256, 0, stream>>>(idx4, counts);
    scan_kernel<<<NB / (SCAN_BLK * 4), SCAN_BLK, 0, stream>>>(
        reinterpret_cast<const int4*>(counts), gtotal,
        reinterpret_cast<int4*>(cursors));
    scatter_kernel<<<2048, 256, 0, stream>>>(idx4, cursors, sorted);
    gather_kernel<<<NB / 64, 256, 0, stream>>>(
        reinterpret_cast<const float4*>(x), counts, cursors, sorted, out);
}